// Round 1
// baseline (86.147 us; speedup 1.0000x reference)
//
#include <hip/hip_runtime.h>
#include <hip/hip_bf16.h>
#include <math.h>

// Problem constants (from reference)
#define C_NUM 1000
#define D_NUM 128
#define N_NUM 256
#define NU    63          // D/2 - 1

// Cephes i0e Chebyshev coefficients, x > 8 branch (double precision).
// i0e(x) = chbevl(32/x - 2, B, 25) / sqrt(x)
__device__ __constant__ double CHEB_B[25] = {
    -7.23318048787475395456E-18, -4.83050448594418207126E-18,
     4.46562142029675999901E-17,  3.46122286769746109310E-17,
    -2.82762398051658348494E-16, -3.42548561967721913462E-16,
     1.77256013305652638360E-15,  3.81168066935262242075E-15,
    -9.55484669882830764870E-15, -4.15056934728722208663E-14,
     1.54008621752140982691E-14,  3.85277838274214270114E-13,
     7.18012445138366623367E-13, -1.79417853150680611778E-12,
    -1.32158118404477131188E-11, -3.14991652796324136454E-11,
     1.18891471078464383424E-11,  4.94060238822496958910E-10,
     3.39623202570838634515E-9,   2.26666899049817806459E-8,
     2.04891858946906374183E-7,   2.89137052083475648297E-6,
     6.88975834691682398426E-5,   3.36911647825569408990E-3,
     8.04490411014108831608E-1
};

// log(ive_NU(x)) for x >= ~99 (always true here: kappa in [100,2000], |f|=1).
// Raw Miller backward recurrence in f64 (no per-step logs): B_126=1, B_127=0,
// B_{i-1} = (2i/x) B_i + B_{i+1}.  B_0 <= ~e^75 -> no overflow in double.
// Anchor: log ive_nu = log( i0e(x) * B_NU / B_0 ).
__device__ __forceinline__ double log_ive_nu(double x) {
    const double tox = 2.0 / x;
    double Bp = 0.0;   // B_{i+1}
    double Bc = 1.0;   // B_i  (start i = 2*NU = 126)
    double di = 126.0;

    // i = 126 .. 64  (63 iterations) -> ends with Bc = B_63 = B_NU
    #pragma unroll 7
    for (int it = 0; it < 63; ++it) {
        double Bn = fma(tox * di, Bc, Bp);
        Bp = Bc; Bc = Bn; di -= 1.0;
    }
    const double Bnu = Bc;

    // i = 63 .. 1  (63 iterations) -> ends with Bc = B_0
    #pragma unroll 7
    for (int it = 0; it < 63; ++it) {
        double Bn = fma(tox * di, Bc, Bp);
        Bp = Bc; Bc = Bn; di -= 1.0;
    }
    const double B0 = Bc;

    // i0e(x), Cephes x>8 branch
    double y  = fma(32.0, 1.0 / x, -2.0);
    double b0 = CHEB_B[0], b1 = 0.0, b2 = 0.0;
    #pragma unroll
    for (int i = 1; i < 25; ++i) {
        b2 = b1; b1 = b0;
        b0 = y * b1 - b2 + CHEB_B[i];
    }
    double i0e = (0.5 * (b0 - b2)) / sqrt(x);

    return log(i0e * (Bnu / B0));
}

// K1: protoT[d][c] = kappa[c] * Ave[c][d] / max(||Ave[c]||, 1e-12)
// one block (64 threads = 1 wave) per class; transposed store for later coalescing.
__global__ __launch_bounds__(64) void prep_proto_kernel(
        const float* __restrict__ Ave, const float* __restrict__ kappa,
        float* __restrict__ protoT) {
    const int c = blockIdx.x;
    const int t = threadIdx.x;
    float a0 = Ave[c * D_NUM + t];
    float a1 = Ave[c * D_NUM + t + 64];
    float ss = a0 * a0 + a1 * a1;
    #pragma unroll
    for (int m = 32; m; m >>= 1) ss += __shfl_xor(ss, m, 64);
    float nrm = fmaxf(sqrtf(ss), 1e-12f);
    float s   = kappa[c] / nrm;
    protoT[t * C_NUM + c]        = a0 * s;
    protoT[(t + 64) * C_NUM + c] = a1 * s;
}

// K2: kn[n][c] = || protoT[:,c] + f[n,:] ||  (f32 accumulation, like reference)
// block = NT rows of N x 256 c-threads (4 c per thread); features in LDS (broadcast reads).
#define NT 2
__global__ __launch_bounds__(256) void kappa_new_kernel(
        const float* __restrict__ features, const float* __restrict__ protoT,
        float* __restrict__ kn) {
    __shared__ float sf[NT][D_NUM];
    const int n0  = blockIdx.x * NT;
    const int tid = threadIdx.x;
    sf[tid >> 7][tid & 127] = features[n0 * D_NUM + tid];  // 256 threads = NT*128 floats
    __syncthreads();

    float acc[NT][4] = {};
    int cc[4];
    #pragma unroll
    for (int k = 0; k < 4; ++k) cc[k] = min(tid + k * 256, C_NUM - 1);

    #pragma unroll 4
    for (int d = 0; d < D_NUM; ++d) {
        const float f0 = sf[0][d];
        const float f1 = sf[1][d];
        #pragma unroll
        for (int k = 0; k < 4; ++k) {
            float p  = protoT[d * C_NUM + cc[k]];
            float t0 = p + f0; acc[0][k] = fmaf(t0, t0, acc[0][k]);
            float t1 = p + f1; acc[1][k] = fmaf(t1, t1, acc[1][k]);
        }
    }
    #pragma unroll
    for (int k = 0; k < 4; ++k) {
        int c = tid + k * 256;
        if (c < C_NUM) {
            kn[n0 * C_NUM + c]       = sqrtf(acc[0][k]);
            kn[(n0 + 1) * C_NUM + c] = sqrtf(acc[1][k]);
        }
    }
}

// K3: elementwise Bessel + assembly of logits. 256000 = 1000 blocks x 256 exactly.
__global__ __launch_bounds__(256) void logits_kernel(
        const float* __restrict__ kn, const float* __restrict__ logc,
        float* __restrict__ out) {
    const int idx = blockIdx.x * 256 + threadIdx.x;
    const int c   = idx % C_NUM;
    const float x_f = kn[idx];
    const double lnu = log_ive_nu((double)x_f);
    out[idx] = (float)lnu + x_f - 63.0f * logf(x_f + 1e-20f) - logc[c];
}

extern "C" void kernel_launch(void* const* d_in, const int* in_sizes, int n_in,
                              void* d_out, int out_size, void* d_ws, size_t ws_size,
                              hipStream_t stream) {
    const float* features = (const float*)d_in[0];
    // d_in[1] = labels (int64) — unused by the deterministic forward
    const float* Ave   = (const float*)d_in[2];
    const float* kappa = (const float*)d_in[3];
    const float* logc  = (const float*)d_in[4];
    float* out = (float*)d_out;

    float* protoT = (float*)d_ws;                          // 128*1000*4 = 512000 B
    float* kn     = (float*)((char*)d_ws + (512u << 10));  // 256*1000*4 = 1024000 B

    prep_proto_kernel<<<C_NUM, 64, 0, stream>>>(Ave, kappa, protoT);
    kappa_new_kernel<<<N_NUM / NT, 256, 0, stream>>>(features, protoT, kn);
    logits_kernel<<<(N_NUM * C_NUM) / 256, 256, 0, stream>>>(kn, logc, out);
}

// Round 2
// 75.989 us; speedup vs baseline: 1.1337x; 1.1337x over previous
//
#include <hip/hip_runtime.h>
#include <hip/hip_bf16.h>
#include <math.h>

#define C_NUM 1000
#define D_NUM 128
#define N_NUM 256
#define NU    63            // D/2 - 1
#define PSTRIDE 1024        // padded row stride of P2T [d][c]

// Cephes i0e Chebyshev coefficients, x > 8 branch (double precision).
__device__ __constant__ double CHEB_B[25] = {
    -7.23318048787475395456E-18, -4.83050448594418207126E-18,
     4.46562142029675999901E-17,  3.46122286769746109310E-17,
    -2.82762398051658348494E-16, -3.42548561967721913462E-16,
     1.77256013305652638360E-15,  3.81168066935262242075E-15,
    -9.55484669882830764870E-15, -4.15056934728722208663E-14,
     1.54008621752140982691E-14,  3.85277838274214270114E-13,
     7.18012445138366623367E-13, -1.79417853150680611778E-12,
    -1.32158118404477131188E-11, -3.14991652796324136454E-11,
     1.18891471078464383424E-11,  4.94060238822496958910E-10,
     3.39623202570838634515E-9,   2.26666899049817806459E-8,
     2.04891858946906374183E-7,   2.89137052083475648297E-6,
     6.88975834691682398426E-5,   3.36911647825569408990E-3,
     8.04490411014108831608E-1
};

// Paired log(ive_NU(x)) for two independent x >= ~99. Raw Miller backward
// recurrence in f64 (no per-step logs): B_126=1, B_127=0,
// B_{i-1} = (2i/x) B_i + B_{i+1}.  B_0 <= ~e^75 -> no overflow in double.
// Two chains interleaved for ILP; di countdown shared.
__device__ __forceinline__ void log_ive_nu2(double x0, double x1,
                                            double* r0, double* r1) {
    const double t0 = 2.0 / x0, t1 = 2.0 / x1;
    double Bp0 = 0.0, Bc0 = 1.0;
    double Bp1 = 0.0, Bc1 = 1.0;
    double di = 126.0;

    // i = 126 .. 64 -> Bc = B_NU
    #pragma unroll 9
    for (int it = 0; it < 63; ++it) {
        double n0 = fma(t0 * di, Bc0, Bp0);
        double n1 = fma(t1 * di, Bc1, Bp1);
        Bp0 = Bc0; Bc0 = n0;
        Bp1 = Bc1; Bc1 = n1;
        di -= 1.0;
    }
    const double Bnu0 = Bc0, Bnu1 = Bc1;

    // i = 63 .. 1 -> Bc = B_0
    #pragma unroll 9
    for (int it = 0; it < 63; ++it) {
        double n0 = fma(t0 * di, Bc0, Bp0);
        double n1 = fma(t1 * di, Bc1, Bp1);
        Bp0 = Bc0; Bc0 = n0;
        Bp1 = Bc1; Bc1 = n1;
        di -= 1.0;
    }

    // i0e(x) via Cephes x>8 branch, both lanes interleaved
    double y0 = fma(32.0, 1.0 / x0, -2.0);
    double y1 = fma(32.0, 1.0 / x1, -2.0);
    double a0 = CHEB_B[0], a1 = 0.0, a2 = 0.0;
    double c0 = CHEB_B[0], c1 = 0.0, c2 = 0.0;
    #pragma unroll
    for (int i = 1; i < 25; ++i) {
        a2 = a1; a1 = a0; a0 = y0 * a1 - a2 + CHEB_B[i];
        c2 = c1; c1 = c0; c0 = y1 * c1 - c2 + CHEB_B[i];
    }
    double i0e0 = (0.5 * (a0 - a2)) / sqrt(x0);
    double i0e1 = (0.5 * (c0 - c2)) / sqrt(x1);

    *r0 = log(i0e0 * (Bnu0 / Bc0));
    *r1 = log(i0e1 * (Bnu1 / Bc1));
}

// Prep kernel: blocks 0..249 (4 classes/block, one wave each):
//   s_c = kappa[c]/max(||Ave_c||,1e-12);  P2T[d][c] = 2*s_c*Ave[c][d];  k2c[c]=kappa^2
// block 250: fn2[n] = ||features[n]||^2
__global__ __launch_bounds__(256) void prep_kernel(
        const float* __restrict__ Ave, const float* __restrict__ kappa,
        const float* __restrict__ features,
        float* __restrict__ P2T, float* __restrict__ k2c, float* __restrict__ fn2) {
    if (blockIdx.x < 250) {
        const int w = threadIdx.x >> 6;      // wave -> class within block
        const int l = threadIdx.x & 63;
        const int c = blockIdx.x * 4 + w;    // < 1000
        float a0 = Ave[c * D_NUM + l];
        float a1 = Ave[c * D_NUM + l + 64];
        float ss = a0 * a0 + a1 * a1;
        #pragma unroll
        for (int m = 32; m; m >>= 1) ss += __shfl_xor(ss, m, 64);
        float nrm = fmaxf(sqrtf(ss), 1e-12f);
        float kap = kappa[c];
        float s2  = 2.0f * kap / nrm;
        P2T[l * PSTRIDE + c]        = a0 * s2;
        P2T[(l + 64) * PSTRIDE + c] = a1 * s2;
        if (l == 0) k2c[c] = kap * kap;
    } else {
        const int n = threadIdx.x;           // N_NUM == 256
        const float4* fr = (const float4*)(features + n * D_NUM);
        float s = 0.0f;
        #pragma unroll
        for (int i = 0; i < D_NUM / 4; ++i) {
            float4 v = fr[i];
            s += v.x * v.x + v.y * v.y + v.z * v.z + v.w * v.w;
        }
        fn2[n] = s;
    }
}

// Fused kernel: grid (4 c-groups, 128 n-groups), 256 threads.
// Each thread: one class c, two rows n0/n0+1.
//   kappa'^2 = k2c[c] + fn2[n] + sum_d P2T[d][c]*f[n][d]
// then paired f64 Bessel + logit assembly.
__global__ __launch_bounds__(256) void fused_kernel(
        const float* __restrict__ P2T, const float* __restrict__ k2c,
        const float* __restrict__ fn2, const float* __restrict__ features,
        const float* __restrict__ logc, float* __restrict__ out) {
    __shared__ float2 sf[D_NUM];
    const int t  = threadIdx.x;
    const int c  = blockIdx.x * 256 + t;
    const int cl = min(c, C_NUM - 1);
    const int n0 = blockIdx.y * 2;

    if (t < D_NUM) {
        sf[t] = make_float2(features[n0 * D_NUM + t],
                            features[(n0 + 1) * D_NUM + t]);
    }
    __syncthreads();

    float acc0 = 0.0f, acc1 = 0.0f;
    #pragma unroll 16
    for (int d = 0; d < D_NUM; ++d) {
        float  p = P2T[d * PSTRIDE + cl];
        float2 f = sf[d];
        acc0 = fmaf(p, f.x, acc0);
        acc1 = fmaf(p, f.y, acc1);
    }

    const float k2 = k2c[cl];
    const float x0 = sqrtf(k2 + fn2[n0]     + acc0);
    const float x1 = sqrtf(k2 + fn2[n0 + 1] + acc1);

    double l0, l1;
    log_ive_nu2((double)x0, (double)x1, &l0, &l1);

    const float lc = logc[cl];
    const float r0 = (float)l0 + x0 - 63.0f * logf(x0 + 1e-20f) - lc;
    const float r1 = (float)l1 + x1 - 63.0f * logf(x1 + 1e-20f) - lc;

    if (c < C_NUM) {
        out[n0 * C_NUM + c]       = r0;
        out[(n0 + 1) * C_NUM + c] = r1;
    }
}

extern "C" void kernel_launch(void* const* d_in, const int* in_sizes, int n_in,
                              void* d_out, int out_size, void* d_ws, size_t ws_size,
                              hipStream_t stream) {
    const float* features = (const float*)d_in[0];
    // d_in[1] = labels (int64) — unused by the deterministic forward
    const float* Ave   = (const float*)d_in[2];
    const float* kappa = (const float*)d_in[3];
    const float* logc  = (const float*)d_in[4];
    float* out = (float*)d_out;

    float* P2T = (float*)d_ws;                                  // 128*1024*4 = 524288 B
    float* k2c = (float*)((char*)d_ws + 524288);                // 1000*4
    float* fn2 = (float*)((char*)d_ws + 524288 + 4096);         // 256*4

    prep_kernel<<<251, 256, 0, stream>>>(Ave, kappa, features, P2T, k2c, fn2);
    fused_kernel<<<dim3(4, 128), 256, 0, stream>>>(P2T, k2c, fn2, features, logc, out);
}

// Round 3
// 75.764 us; speedup vs baseline: 1.1370x; 1.0030x over previous
//
#include <hip/hip_runtime.h>
#include <hip/hip_bf16.h>
#include <math.h>

#define C_NUM 1000
#define D_NUM 128
#define N_NUM 256
#define NU    63            // D/2 - 1

// Cephes i0e Chebyshev coefficients, x > 8 branch (double precision).
__device__ __constant__ double CHEB_B[25] = {
    -7.23318048787475395456E-18, -4.83050448594418207126E-18,
     4.46562142029675999901E-17,  3.46122286769746109310E-17,
    -2.82762398051658348494E-16, -3.42548561967721913462E-16,
     1.77256013305652638360E-15,  3.81168066935262242075E-15,
    -9.55484669882830764870E-15, -4.15056934728722208663E-14,
     1.54008621752140982691E-14,  3.85277838274214270114E-13,
     7.18012445138366623367E-13, -1.79417853150680611778E-12,
    -1.32158118404477131188E-11, -3.14991652796324136454E-11,
     1.18891471078464383424E-11,  4.94060238822496958910E-10,
     3.39623202570838634515E-9,   2.26666899049817806459E-8,
     2.04891858946906374183E-7,   2.89137052083475648297E-6,
     6.88975834691682398426E-5,   3.36911647825569408990E-3,
     8.04490411014108831608E-1
};

// Paired log(ive_NU(x)) for two independent x >= ~99. Raw Miller backward
// recurrence in f64 (no per-step logs): B_126=1, B_127=0,
// B_{i-1} = (2i/x) B_i + B_{i+1}.  B_0 <= ~e^75 -> no overflow in double.
// Two chains interleaved for ILP; di countdown shared.
__device__ __forceinline__ void log_ive_nu2(double x0, double x1,
                                            double* r0, double* r1) {
    const double t0 = 2.0 / x0, t1 = 2.0 / x1;
    double Bp0 = 0.0, Bc0 = 1.0;
    double Bp1 = 0.0, Bc1 = 1.0;
    double di = 126.0;

    // i = 126 .. 64 -> Bc = B_NU
    #pragma unroll 9
    for (int it = 0; it < 63; ++it) {
        double n0 = fma(t0 * di, Bc0, Bp0);
        double n1 = fma(t1 * di, Bc1, Bp1);
        Bp0 = Bc0; Bc0 = n0;
        Bp1 = Bc1; Bc1 = n1;
        di -= 1.0;
    }
    const double Bnu0 = Bc0, Bnu1 = Bc1;

    // i = 63 .. 1 -> Bc = B_0
    #pragma unroll 9
    for (int it = 0; it < 63; ++it) {
        double n0 = fma(t0 * di, Bc0, Bp0);
        double n1 = fma(t1 * di, Bc1, Bp1);
        Bp0 = Bc0; Bc0 = n0;
        Bp1 = Bc1; Bc1 = n1;
        di -= 1.0;
    }

    // i0e(x) via Cephes x>8 branch, both lanes interleaved
    double y0 = fma(32.0, 1.0 / x0, -2.0);
    double y1 = fma(32.0, 1.0 / x1, -2.0);
    double a0 = CHEB_B[0], a1 = 0.0, a2 = 0.0;
    double c0 = CHEB_B[0], c1 = 0.0, c2 = 0.0;
    #pragma unroll
    for (int i = 1; i < 25; ++i) {
        a2 = a1; a1 = a0; a0 = y0 * a1 - a2 + CHEB_B[i];
        c2 = c1; c1 = c0; c0 = y1 * c1 - c2 + CHEB_B[i];
    }
    double i0e0 = (0.5 * (a0 - a2)) / sqrt(x0);
    double i0e1 = (0.5 * (c0 - c2)) / sqrt(x1);

    *r0 = log(i0e0 * (Bnu0 / Bc0));
    *r1 = log(i0e1 * (Bnu1 / Bc1));
}

// Single fused kernel. Grid (4 c-groups, 128 n-groups) x 256 threads.
// Thread t of c-group b owns class c = b*256+t and rows n0, n0+1.
// One pass over Ave row (float4, L2-resident) accumulates Sa2 = ||Ave_c||^2,
// acc0/1 = Ave_c . f_n, while Sf0/1 = ||f_n||^2 accumulate from LDS.
//   kappa'^2 = kappa^2 + ||f||^2 + (2*kappa/||Ave_c||) * (Ave_c . f)
// then paired f64 Miller recurrence + logit assembly.
__global__ __launch_bounds__(256) void procoun_kernel(
        const float* __restrict__ features, const float* __restrict__ Ave,
        const float* __restrict__ kappa, const float* __restrict__ logc,
        float* __restrict__ out) {
    __shared__ float2 sf[D_NUM];
    const int t  = threadIdx.x;
    const int c  = blockIdx.x * 256 + t;
    const int cl = min(c, C_NUM - 1);
    const int n0 = blockIdx.y * 2;

    if (t < D_NUM) {
        sf[t] = make_float2(features[n0 * D_NUM + t],
                            features[(n0 + 1) * D_NUM + t]);
    }
    __syncthreads();

    const float4* arow = (const float4*)(Ave + cl * D_NUM);
    float acc0 = 0.0f, acc1 = 0.0f, Sa2 = 0.0f, Sf0 = 0.0f, Sf1 = 0.0f;
    #pragma unroll 8
    for (int q = 0; q < D_NUM / 4; ++q) {
        float4 a = arow[q];
        float2 f0 = sf[q * 4 + 0];
        float2 f1 = sf[q * 4 + 1];
        float2 f2 = sf[q * 4 + 2];
        float2 f3 = sf[q * 4 + 3];
        Sa2  = fmaf(a.x, a.x, Sa2);  Sa2  = fmaf(a.y, a.y, Sa2);
        Sa2  = fmaf(a.z, a.z, Sa2);  Sa2  = fmaf(a.w, a.w, Sa2);
        acc0 = fmaf(a.x, f0.x, acc0); acc1 = fmaf(a.x, f0.y, acc1);
        acc0 = fmaf(a.y, f1.x, acc0); acc1 = fmaf(a.y, f1.y, acc1);
        acc0 = fmaf(a.z, f2.x, acc0); acc1 = fmaf(a.z, f2.y, acc1);
        acc0 = fmaf(a.w, f3.x, acc0); acc1 = fmaf(a.w, f3.y, acc1);
        Sf0  = fmaf(f0.x, f0.x, Sf0); Sf1  = fmaf(f0.y, f0.y, Sf1);
        Sf0  = fmaf(f1.x, f1.x, Sf0); Sf1  = fmaf(f1.y, f1.y, Sf1);
        Sf0  = fmaf(f2.x, f2.x, Sf0); Sf1  = fmaf(f2.y, f2.y, Sf1);
        Sf0  = fmaf(f3.x, f3.x, Sf0); Sf1  = fmaf(f3.y, f3.y, Sf1);
    }

    const float kap = kappa[cl];
    const float s2  = 2.0f * kap / fmaxf(sqrtf(Sa2), 1e-12f);
    const float k2  = kap * kap;
    const float x0  = sqrtf(fmaf(s2, acc0, k2 + Sf0));
    const float x1  = sqrtf(fmaf(s2, acc1, k2 + Sf1));

    double l0, l1;
    log_ive_nu2((double)x0, (double)x1, &l0, &l1);

    const float lc = logc[cl];
    const float r0 = (float)l0 + x0 - 63.0f * logf(x0 + 1e-20f) - lc;
    const float r1 = (float)l1 + x1 - 63.0f * logf(x1 + 1e-20f) - lc;

    if (c < C_NUM) {
        out[n0 * C_NUM + c]       = r0;
        out[(n0 + 1) * C_NUM + c] = r1;
    }
}

extern "C" void kernel_launch(void* const* d_in, const int* in_sizes, int n_in,
                              void* d_out, int out_size, void* d_ws, size_t ws_size,
                              hipStream_t stream) {
    const float* features = (const float*)d_in[0];
    // d_in[1] = labels (int64) — unused by the deterministic forward
    const float* Ave   = (const float*)d_in[2];
    const float* kappa = (const float*)d_in[3];
    const float* logc  = (const float*)d_in[4];
    float* out = (float*)d_out;

    procoun_kernel<<<dim3(4, 128), 256, 0, stream>>>(features, Ave, kappa, logc, out);
}